// Round 7
// baseline (83.087 us; speedup 1.0000x reference)
//
#include <hip/hip_runtime.h>

// VQ-VAE vector quantizer, MI355X — v5: occupancy-first score kernel.
// 256-thr blocks, T=64 token tile (35.5KB LDS), 4 interleaved MFMA chains,
// bias via LDS, launch_bounds(256,4) for 4 waves/SIMD.
// score(t,k) = x_t . e_k - 0.5*||e_k||^2  (argmax == argmin distance)
// x.e = xh.eh + (xh.el' + xl'.eh)/2048, *_lo' = (v - fp16(v))*2048 as fp16.

typedef _Float16 f16;
typedef _Float16 f16x4 __attribute__((ext_vector_type(4)));
typedef _Float16 f16x8 __attribute__((ext_vector_type(8)));
typedef float f32x16 __attribute__((ext_vector_type(16)));

#define ND 128
#define NK 512
#define NHW 4096
#define NTOK 65536
#define LO_SCALE 2048.0f
#define LO_INV (1.0f / 2048.0f)
#define TT 64          // tokens per score tile
#define KCH 256        // codes per chunk

// workspace layout (bytes)
#define WS_XHI 0
#define WS_XLO 16777216u
#define WS_EHI 33554432u
#define WS_ELO 33685504u
#define WS_ENS 33816576u
#define WS_NEED_V3 33818624u
#define WS_WIN 33818624u
#define WS_NEED_V4 34342912u

__device__ __forceinline__ unsigned mono_key(float v) {
  const unsigned u = __float_as_uint(v);
  return (u & 0x80000000u) ? ~u : (u | 0x80000000u);
}

// ================================================================ prep ======
// blocks 0..1023: transpose+split x (SWIZZLED slots)
// blocks 1024..1055: split e PLAIN + 0.5*||e||^2
// blocks 1056..1311: zero winners
__global__ __launch_bounds__(256) void vq_prep3(const float* __restrict__ x,
                                                const float* __restrict__ e,
                                                f16* __restrict__ xhi, f16* __restrict__ xlo,
                                                f16* __restrict__ ehi, f16* __restrict__ elo,
                                                float* __restrict__ ens,
                                                unsigned long long* __restrict__ win) {
  const int tid = threadIdx.x;
  if (blockIdx.x < 1024) {
    __shared__ float sc[ND][65];
    const int tok0 = blockIdx.x * 64;
    const int b = blockIdx.x >> 6;
    const int hw0 = (blockIdx.x & 63) * 64;
    const float* xb = x + (size_t)b * ND * NHW + hw0;
    #pragma unroll
    for (int it = 0; it < 8; ++it) {
      const int f = tid + 256 * it;
      const int d = f >> 4, t4 = (f & 15) * 4;
      const float4 v = *(const float4*)(xb + (size_t)d * NHW + t4);
      sc[d][t4 + 0] = v.x; sc[d][t4 + 1] = v.y;
      sc[d][t4 + 2] = v.z; sc[d][t4 + 3] = v.w;
    }
    __syncthreads();
    const int oct = tid & 15, trow = tid >> 4;
    #pragma unroll
    for (int p = 0; p < 4; ++p) {
      const int t = p * 16 + trow;
      const int tok = tok0 + t;
      float v[8];
      #pragma unroll
      for (int j = 0; j < 8; ++j) v[j] = sc[oct * 8 + j][t];
      f16x8 h, l;
      #pragma unroll
      for (int j = 0; j < 8; ++j) {
        const f16 hv = (f16)v[j];
        h[j] = hv;
        l[j] = (f16)((v[j] - (float)hv) * LO_SCALE);
      }
      const size_t off = (size_t)tok * ND + (size_t)((oct ^ (tok & 15)) * 8);
      *(f16x8*)(xhi + off) = h;
      *(f16x8*)(xlo + off) = l;
    }
  } else if (blockIdx.x < 1056) {
    const int k0 = ((int)blockIdx.x - 1024) * 16;
    const int r = tid >> 4, dq16 = tid & 15;
    const int k = k0 + r;
    float ssum = 0.0f;
    #pragma unroll
    for (int hh = 0; hh < 2; ++hh) {
      const int dq = dq16 + 16 * hh;
      const float4 v = *(const float4*)(e + (size_t)k * ND + 4 * dq);
      ssum += v.x * v.x + v.y * v.y + v.z * v.z + v.w * v.w;
      float va[4] = {v.x, v.y, v.z, v.w};
      f16x4 hv, lv;
      #pragma unroll
      for (int j = 0; j < 4; ++j) {
        const f16 h = (f16)va[j];
        hv[j] = h;
        lv[j] = (f16)((va[j] - (float)h) * LO_SCALE);
      }
      const size_t off = (size_t)k * ND + 4 * dq;   // PLAIN layout
      *(f16x4*)(ehi + off) = hv;
      *(f16x4*)(elo + off) = lv;
    }
    #pragma unroll
    for (int m = 1; m < 16; m <<= 1) ssum += __shfl_xor(ssum, m, 64);
    if (dq16 == 0) ens[k] = 0.5f * ssum;
  } else {
    win[((int)blockIdx.x - 1056) * 256 + tid] = 0ull;
  }
}

// =============================================================== score ======
// grid 2048 = 1024 token-tiles(64) x 2 code-chunks(256). 4 waves/block.
// wave w: codes c*256 + w*64 .. +64 (2 cgroups of 32, A in regs);
// x tile hi/lo in LDS (B); 4 interleaved acc chains per cgroup.
__global__ __launch_bounds__(256, 4) void vq_score(const f16* __restrict__ xhi,
                                                   const f16* __restrict__ xlo,
                                                   const f16* __restrict__ ehi,
                                                   const f16* __restrict__ elo,
                                                   const float* __restrict__ ens,
                                                   unsigned long long* __restrict__ win) {
  __shared__ f16 xsh[TT * 128];                // 16KB (swizzled slots)
  __shared__ f16 xsl[TT * 128];                // 16KB
  __shared__ float ens_s[KCH];                 // 1KB
  __shared__ unsigned long long cand[TT][5];   // 2.5KB (+pad col)

  const int tid = threadIdx.x;                 // 0..255
  const int w = tid >> 6;                      // wave 0..3
  const int lane = tid & 63;
  const int l31 = lane & 31;
  const int half = lane >> 5;
  const int tile = (int)blockIdx.x >> 1;
  const int c = (int)blockIdx.x & 1;
  const int T0 = tile * TT;
  const int cw = c * KCH + w * 64;             // wave's 64-code base

  // stage x tile: pre-swizzled global -> regs -> linear LDS
  uint4 r0[4], r1[4];
  {
    const f16* sh = xhi + (size_t)T0 * ND;
    const f16* sl = xlo + (size_t)T0 * ND;
    #pragma unroll
    for (int p = 0; p < 4; ++p) {
      r0[p] = *(const uint4*)(sh + p * 2048 + tid * 8);
      r1[p] = *(const uint4*)(sl + p * 2048 + tid * 8);
    }
  }
  #pragma unroll
  for (int p = 0; p < 4; ++p) {
    *(uint4*)&xsh[p * 2048 + tid * 8] = r0[p];
    *(uint4*)&xsl[p * 2048 + tid * 8] = r1[p];
  }
  ens_s[tid] = ens[c * KCH + tid];
  __syncthreads();

  unsigned long long best[2] = {0ull, 0ull};   // per ni (token group)

  #pragma unroll
  for (int cg = 0; cg < 2; ++cg) {
    // A fragments: this lane's code row (e hi/lo, plain layout), 8 k-steps
    const int acode = cw + cg * 32 + l31;
    f16x8 Ah[8], Al[8];
    #pragma unroll
    for (int ks = 0; ks < 8; ++ks) {
      const size_t off = (size_t)acode * ND + ks * 16 + half * 8;
      Ah[ks] = *(const f16x8*)(ehi + off);
      Al[ks] = *(const f16x8*)(elo + off);
    }

    f32x16 a1_0 = {}, a1_1 = {}, a2_0 = {}, a2_1 = {};
    __builtin_amdgcn_s_setprio(1);
    #pragma unroll
    for (int ks = 0; ks < 8; ++ks) {
      const int sl = ((2 * ks + half) ^ (l31 & 15)) * 8;  // tt&15 == l31&15
      const f16x8 bh0 = *(const f16x8*)&xsh[l31 * 128 + sl];
      const f16x8 bh1 = *(const f16x8*)&xsh[(32 + l31) * 128 + sl];
      const f16x8 bl0 = *(const f16x8*)&xsl[l31 * 128 + sl];
      const f16x8 bl1 = *(const f16x8*)&xsl[(32 + l31) * 128 + sl];
      a2_0 = __builtin_amdgcn_mfma_f32_32x32x16_f16(Al[ks], bh0, a2_0, 0, 0, 0);
      a2_1 = __builtin_amdgcn_mfma_f32_32x32x16_f16(Al[ks], bh1, a2_1, 0, 0, 0);
      a1_0 = __builtin_amdgcn_mfma_f32_32x32x16_f16(Ah[ks], bh0, a1_0, 0, 0, 0);
      a1_1 = __builtin_amdgcn_mfma_f32_32x32x16_f16(Ah[ks], bh1, a1_1, 0, 0, 0);
      a2_0 = __builtin_amdgcn_mfma_f32_32x32x16_f16(Ah[ks], bl0, a2_0, 0, 0, 0);
      a2_1 = __builtin_amdgcn_mfma_f32_32x32x16_f16(Ah[ks], bl1, a2_1, 0, 0, 0);
    }
    __builtin_amdgcn_s_setprio(0);

    // scores + lane-local argmax, per token group
    #pragma unroll
    for (int ni = 0; ni < 2; ++ni) {
      float bv = -3.0e38f; int bi = 0;
      #pragma unroll
      for (int r = 0; r < 16; ++r) {
        const int rowr = (r & 3) + 8 * (r >> 2) + 4 * half;
        const int kloc = w * 64 + cg * 32 + rowr;   // code within chunk
        const float hi = (ni == 0) ? a1_0[r] : a1_1[r];
        const float lo = (ni == 0) ? a2_0[r] : a2_1[r];
        const float s = hi + lo * LO_INV - ens_s[kloc];
        const int cd = c * KCH + kloc;
        if (s > bv) { bv = s; bi = cd; }   // rowr ascends with r: strict > keeps lowest
      }
      // merge across halves (same token for lane ^ 32)
      const float ov = __shfl_xor(bv, 32, 64);
      const int oi = __shfl_xor(bi, 32, 64);
      if (ov > bv || (ov == bv && oi < bi)) { bv = ov; bi = oi; }
      const unsigned long long key =
          ((unsigned long long)mono_key(bv) << 32) | (unsigned)(511 - bi);
      best[ni] = (key > best[ni]) ? key : best[ni];
    }
  }

  if (half == 0) {
    cand[l31][w] = best[0];
    cand[32 + l31][w] = best[1];
  }
  __syncthreads();
  if (tid < TT) {
    unsigned long long k = cand[tid][0];
    #pragma unroll
    for (int j = 1; j < 4; ++j) {
      const unsigned long long kj = cand[tid][j];
      k = (kj > k) ? kj : k;
    }
    atomicMax(win + T0 + tid, k);
  }
}

// ============================================================== scatter =====
__global__ __launch_bounds__(512) void vq_scatter(const unsigned long long* __restrict__ win,
                                                  const float* __restrict__ e32,
                                                  float* __restrict__ out) {
  __shared__ int bidx_s[128];
  const int tid = threadIdx.x;
  const int T0 = (int)blockIdx.x * 128;
  if (tid < 128) bidx_s[tid] = 511 - (int)(win[T0 + tid] & 0x1FFull);
  __syncthreads();
  const int tloc = tid & 127, dg = tid >> 7;
  const int Tg = T0 + tloc;
  const int bb = Tg >> 12;
  const int hw = Tg & 4095;
  const float* er = e32 + (size_t)bidx_s[tloc] * ND;
  float* ob = out + (size_t)bb * ND * NHW + hw;
  #pragma unroll
  for (int j4 = 0; j4 < 8; ++j4) {
    const int d = dg * 32 + j4 * 4;
    const float4 ev = *(const float4*)(er + d);
    ob[(size_t)(d + 0) * NHW] = ev.x;
    ob[(size_t)(d + 1) * NHW] = ev.y;
    ob[(size_t)(d + 2) * NHW] = ev.z;
    ob[(size_t)(d + 3) * NHW] = ev.w;
  }
}

// ====================================================== v3 middle tier ======
__global__ __launch_bounds__(256) void vq_prep2(const float* __restrict__ x,
                                                const float* __restrict__ e,
                                                f16* __restrict__ xhi, f16* __restrict__ xlo,
                                                f16* __restrict__ ehi, f16* __restrict__ elo,
                                                float* __restrict__ ens) {
  const int tid = threadIdx.x;
  if (blockIdx.x < 1024) {
    __shared__ float sc[ND][65];
    const int tok0 = blockIdx.x * 64;
    const int b = blockIdx.x >> 6;
    const int hw0 = (blockIdx.x & 63) * 64;
    const float* xb = x + (size_t)b * ND * NHW + hw0;
    #pragma unroll
    for (int it = 0; it < 8; ++it) {
      const int f = tid + 256 * it;
      const int d = f >> 4, t4 = (f & 15) * 4;
      const float4 v = *(const float4*)(xb + (size_t)d * NHW + t4);
      sc[d][t4 + 0] = v.x; sc[d][t4 + 1] = v.y;
      sc[d][t4 + 2] = v.z; sc[d][t4 + 3] = v.w;
    }
    __syncthreads();
    const int oct = tid & 15, trow = tid >> 4;
    #pragma unroll
    for (int p = 0; p < 4; ++p) {
      const int t = p * 16 + trow;
      float v[8];
      #pragma unroll
      for (int j = 0; j < 8; ++j) v[j] = sc[oct * 8 + j][t];
      f16x8 h, l;
      #pragma unroll
      for (int j = 0; j < 8; ++j) {
        const f16 hv = (f16)v[j];
        h[j] = hv;
        l[j] = (f16)((v[j] - (float)hv) * LO_SCALE);
      }
      const size_t off = (size_t)(tok0 + t) * ND + oct * 8;  // plain x
      *(f16x8*)(xhi + off) = h;
      *(f16x8*)(xlo + off) = l;
    }
  } else {
    const int k0 = ((int)blockIdx.x - 1024) * 16;
    const int r = tid >> 4, dq16 = tid & 15;
    const int k = k0 + r;
    float ssum = 0.0f;
    #pragma unroll
    for (int hh = 0; hh < 2; ++hh) {
      const int dq = dq16 + 16 * hh;
      const float4 v = *(const float4*)(e + (size_t)k * ND + 4 * dq);
      ssum += v.x * v.x + v.y * v.y + v.z * v.z + v.w * v.w;
      float va[4] = {v.x, v.y, v.z, v.w};
      f16x4 hv, lv;
      #pragma unroll
      for (int j = 0; j < 4; ++j) {
        const f16 h = (f16)va[j];
        hv[j] = h;
        lv[j] = (f16)((va[j] - (float)h) * LO_SCALE);
      }
      const int sl = (dq >> 1) ^ (k & 15);               // swizzled e
      const size_t off = (size_t)k * ND + sl * 8 + (dq & 1) * 4;
      *(f16x4*)(ehi + off) = hv;
      *(f16x4*)(elo + off) = lv;
    }
    #pragma unroll
    for (int m = 1; m < 16; m <<= 1) ssum += __shfl_xor(ssum, m, 64);
    if (dq16 == 0) ens[k] = 0.5f * ssum;
  }
}

__global__ __launch_bounds__(512, 2) void vq_mfma(const f16* __restrict__ xhi,
                                                  const f16* __restrict__ xlo,
                                                  const f16* __restrict__ ehi,
                                                  const f16* __restrict__ elo,
                                                  const float* __restrict__ ens,
                                                  const float* __restrict__ e32,
                                                  float* __restrict__ out) {
  __shared__ f16 es[2][2][128 * 128];
  __shared__ float ens_sv[NK];
  __shared__ int bidx_s[256];
  const int tid = threadIdx.x;
  const int w = tid >> 6;
  const int lane = tid & 63;
  const int row32 = lane & 31;
  const int half = lane >> 5;
  const int T0 = blockIdx.x * 256;
  const int tok = T0 + w * 32 + row32;
  ens_sv[tid] = ens[tid];
  uint4 sreg[4][2];
  #pragma unroll
  for (int p = 0; p < 4; ++p) {
    const size_t so = (size_t)p * 4096 + tid * 8;
    sreg[p][0] = *(const uint4*)(ehi + so);
    sreg[p][1] = *(const uint4*)(elo + so);
  }
  f16x8 Ah[8], Al[8];
  #pragma unroll
  for (int ks = 0; ks < 8; ++ks) {
    const size_t off = (size_t)tok * ND + ks * 16 + half * 8;
    Ah[ks] = *(const f16x8*)(xhi + off);
    Al[ks] = *(const f16x8*)(xlo + off);
  }
  #pragma unroll
  for (int p = 0; p < 4; ++p) {
    *(uint4*)&es[0][0][p * 4096 + tid * 8] = sreg[p][0];
    *(uint4*)&es[0][1][p * 4096 + tid * 8] = sreg[p][1];
  }
  __syncthreads();
  float bv[16]; int bi[16];
  #pragma unroll
  for (int r = 0; r < 16; ++r) { bv[r] = -3.0e38f; bi[r] = 0; }
  int cur = 0;
  for (int cc4 = 0; cc4 < 4; ++cc4) {
    if (cc4 < 3) {
      const size_t src0 = (size_t)(cc4 + 1) * 16384;
      #pragma unroll
      for (int p = 0; p < 4; ++p) {
        const size_t so = src0 + p * 4096 + tid * 8;
        sreg[p][0] = *(const uint4*)(ehi + so);
        sreg[p][1] = *(const uint4*)(elo + so);
      }
    }
    const int kb = cc4 * 128;
    for (int ni = 0; ni < 4; ++ni) {
      const int cr = ni * 32 + row32;
      const int code = kb + cr;
      f32x16 acc1 = {}, acc2 = {}, acc3 = {};
      #pragma unroll
      for (int ks = 0; ks < 8; ++ks) {
        const int sl = ((2 * ks + half) ^ (cr & 15)) * 8;
        const f16x8 bh = *(const f16x8*)&es[cur][0][cr * 128 + sl];
        const f16x8 bl = *(const f16x8*)&es[cur][1][cr * 128 + sl];
        acc1 = __builtin_amdgcn_mfma_f32_32x32x16_f16(Ah[ks], bh, acc1, 0, 0, 0);
        acc2 = __builtin_amdgcn_mfma_f32_32x32x16_f16(Ah[ks], bl, acc2, 0, 0, 0);
        acc3 = __builtin_amdgcn_mfma_f32_32x32x16_f16(Al[ks], bh, acc3, 0, 0, 0);
      }
      const float bias = ens_sv[code];
      #pragma unroll
      for (int r = 0; r < 16; ++r) {
        const float s = acc1[r] + (acc2[r] + acc3[r]) * LO_INV - bias;
        if (s > bv[r]) { bv[r] = s; bi[r] = code; }
      }
    }
    __syncthreads();
    if (cc4 < 3) {
      #pragma unroll
      for (int p = 0; p < 4; ++p) {
        *(uint4*)&es[cur ^ 1][0][p * 4096 + tid * 8] = sreg[p][0];
        *(uint4*)&es[cur ^ 1][1][p * 4096 + tid * 8] = sreg[p][1];
      }
    }
    __syncthreads();
    cur ^= 1;
  }
  #pragma unroll
  for (int r = 0; r < 16; ++r) {
    #pragma unroll
    for (int m = 1; m < 32; m <<= 1) {
      const float ov = __shfl_xor(bv[r], m, 64);
      const int oi = __shfl_xor(bi[r], m, 64);
      if (ov > bv[r] || (ov == bv[r] && oi < bi[r])) { bv[r] = ov; bi[r] = oi; }
    }
    const int rowr = (r & 3) + 8 * (r >> 2) + 4 * half;
    if (row32 == r) bidx_s[w * 32 + rowr] = bi[r];
  }
  __syncthreads();
  const int tloc = tid & 255;
  const int dg = tid >> 8;
  const int Tg = T0 + tloc;
  const int bb = Tg >> 12;
  const int hw = Tg & 4095;
  const float* er = e32 + (size_t)bidx_s[tloc] * ND;
  float* ob = out + (size_t)bb * ND * NHW + hw;
  #pragma unroll
  for (int j4 = 0; j4 < 16; ++j4) {
    const int d = dg * 64 + j4 * 4;
    const float4 ev = *(const float4*)(er + d);
    ob[(size_t)(d + 0) * NHW] = ev.x;
    ob[(size_t)(d + 1) * NHW] = ev.y;
    ob[(size_t)(d + 2) * NHW] = ev.z;
    ob[(size_t)(d + 3) * NHW] = ev.w;
  }
}

// ======================================================== fp32 last tier ====
__global__ __launch_bounds__(128) void vq_enorm(const float* __restrict__ e,
                                                float* __restrict__ ensw) {
  const int k = blockIdx.x;
  const int d = threadIdx.x;
  const float v = e[k * ND + d];
  float s = v * v;
  #pragma unroll
  for (int off = 32; off > 0; off >>= 1) s += __shfl_down(s, off, 64);
  __shared__ float tmp[2];
  if ((d & 63) == 0) tmp[d >> 6] = s;
  __syncthreads();
  if (d == 0) ensw[k] = tmp[0] + tmp[1];
}

__global__ __launch_bounds__(256, 2) void vq_main_f32(const float* __restrict__ x,
                                                      const float* __restrict__ e,
                                                      const float* __restrict__ ensw,
                                                      float* __restrict__ out) {
  __shared__ float xs[ND][64];
  __shared__ float esh[ND][64];
  __shared__ float enh[NK];
  __shared__ float red_v[64][17];
  __shared__ int red_i[64][17];
  __shared__ int bidx[64];
  const int tid = threadIdx.x;
  const int b = blockIdx.x >> 6;
  const int hw0 = (blockIdx.x & 63) * 64;
  const float* xb = x + ((size_t)b * ND) * NHW;
  #pragma unroll
  for (int i = 0; i < 8; ++i) {
    const int f = tid + 256 * i;
    const int d = f >> 4, t4 = f & 15;
    const float4 v = *(const float4*)(xb + (size_t)d * NHW + hw0 + 4 * t4);
    *(float4*)&xs[d][4 * t4] = v;
  }
  #pragma unroll
  for (int i = 0; i < 2; ++i) enh[tid + 256 * i] = ensw[tid + 256 * i];
  const int t4 = tid & 15, m = tid >> 4;
  float bvv[4] = {-3.0e38f, -3.0e38f, -3.0e38f, -3.0e38f};
  int bii[4] = {0, 0, 0, 0};
  for (int kc = 0; kc < NK / 64; ++kc) {
    __syncthreads();
    #pragma unroll
    for (int i = 0; i < 8; ++i) {
      const int f = tid + 256 * i;
      const int kk = f & 63, dq = f >> 6;
      const float4 v = *(const float4*)(e + (size_t)(kc * 64 + kk) * ND + 4 * dq);
      esh[4 * dq + 0][kk] = v.x; esh[4 * dq + 1][kk] = v.y;
      esh[4 * dq + 2][kk] = v.z; esh[4 * dq + 3][kk] = v.w;
    }
    __syncthreads();
    float acc[4][4];
    #pragma unroll
    for (int a = 0; a < 4; ++a)
      #pragma unroll
      for (int cc = 0; cc < 4; ++cc) acc[a][cc] = 0.0f;
    #pragma unroll 8
    for (int d = 0; d < ND; ++d) {
      const float4 xv = *(const float4*)&xs[d][4 * t4];
      const float4 ev = *(const float4*)&esh[d][4 * m];
      const float xa[4] = {xv.x, xv.y, xv.z, xv.w};
      const float ea[4] = {ev.x, ev.y, ev.z, ev.w};
      #pragma unroll
      for (int a = 0; a < 4; ++a)
        #pragma unroll
        for (int cc = 0; cc < 4; ++cc) acc[a][cc] = fmaf(xa[a], ea[cc], acc[a][cc]);
    }
    const int kbase = kc * 64 + 4 * m;
    #pragma unroll
    for (int cc = 0; cc < 4; ++cc) {
      const float bias = 0.5f * enh[kbase + cc];
      const int kg = kbase + cc;
      #pragma unroll
      for (int a = 0; a < 4; ++a) {
        const float s = acc[a][cc] - bias;
        if (s > bvv[a] || (s == bvv[a] && kg < bii[a])) { bvv[a] = s; bii[a] = kg; }
      }
    }
  }
  #pragma unroll
  for (int a = 0; a < 4; ++a) { red_v[4 * t4 + a][m] = bvv[a]; red_i[4 * t4 + a][m] = bii[a]; }
  __syncthreads();
  if (tid < 64) {
    float v = red_v[tid][0]; int ix = red_i[tid][0];
    #pragma unroll
    for (int j = 1; j < 16; ++j) {
      const float vj = red_v[tid][j]; const int ij = red_i[tid][j];
      if (vj > v || (vj == v && ij < ix)) { v = vj; ix = ij; }
    }
    bidx[tid] = ix;
  }
  __syncthreads();
  const int t = tid & 63, dgg = tid >> 6;
  const float* er = e + (size_t)bidx[t] * ND;
  float* ob = out + ((size_t)b * ND) * NHW + hw0 + t;
  #pragma unroll
  for (int i = 0; i < 32; ++i) ob[(size_t)(dgg * 32 + i) * NHW] = er[dgg * 32 + i];
}

// --------------------------------------------------------------- launch -----
extern "C" void kernel_launch(void* const* d_in, const int* in_sizes, int n_in,
                              void* d_out, int out_size, void* d_ws, size_t ws_size,
                              hipStream_t stream) {
  const float* x = (const float*)d_in[0];
  const float* e = (const float*)d_in[1];
  float* out = (float*)d_out;
  char* ws = (char*)d_ws;

  f16* xhi = (f16*)(ws + WS_XHI);
  f16* xlo = (f16*)(ws + WS_XLO);
  f16* ehi = (f16*)(ws + WS_EHI);
  f16* elo = (f16*)(ws + WS_ELO);
  float* ens = (float*)(ws + WS_ENS);
  unsigned long long* win = (unsigned long long*)(ws + WS_WIN);

  if (ws_size >= WS_NEED_V4) {
    vq_prep3<<<1312, 256, 0, stream>>>(x, e, xhi, xlo, ehi, elo, ens, win);
    vq_score<<<2048, 256, 0, stream>>>(xhi, xlo, ehi, elo, ens, win);
    vq_scatter<<<512, 512, 0, stream>>>(win, e, out);
  } else if (ws_size >= WS_NEED_V3) {
    vq_prep2<<<1056, 256, 0, stream>>>(x, e, xhi, xlo, ehi, elo, ens);
    vq_mfma<<<256, 512, 0, stream>>>(xhi, xlo, ehi, elo, ens, e, out);
  } else {
    float* ensw = (float*)d_ws;
    vq_enorm<<<NK, 128, 0, stream>>>(e, ensw);
    vq_main_f32<<<16 * 64, 256, 0, stream>>>(x, e, ensw, out);
  }
}